// Round 5
// baseline (1082.525 us; speedup 1.0000x reference)
//
#include <hip/hip_runtime.h>
#include <math.h>

#define D_IN 100
#define H    100
#define SEQL 30

typedef __attribute__((ext_vector_type(8))) short bf16x8;
typedef __attribute__((ext_vector_type(4))) short s16x4;
typedef __attribute__((ext_vector_type(4))) float f32x4;

__device__ __forceinline__ short f2bf(float f) {
    unsigned u = __builtin_bit_cast(unsigned, f);
    unsigned r = (u + 0x7FFFu + ((u >> 16) & 1u)) >> 16;
    return (short)r;
}
__device__ __forceinline__ float bf2f(short s) {
    unsigned u = ((unsigned)(unsigned short)s) << 16;
    return __builtin_bit_cast(float, u);
}

// ---------------------------------------------------------------------------
// Fused weight packing (one launch instead of four).
// ---------------------------------------------------------------------------
__device__ __forceinline__ void bpack_one(const float* __restrict__ W_hh,
                                          short* __restrict__ Bhi,
                                          short* __restrict__ Blo, int t) {
    int i    = t & 7;
    int lane = (t >> 3) & 63;
    int blk  = t >> 9;            // nt*4 + ks
    int ks = blk & 3, nt = blk >> 2;
    int np = nt * 16 + (lane & 15);
    int k  = ks * 32 + ((lane >> 4) << 3) + i;
    int g = np / 112, j = np % 112;
    float v = (j < 100 && k < 100) ? W_hh[(g * 100 + j) * 100 + k] : 0.f;
    short hi = f2bf(v);
    Bhi[t] = hi;
    Blo[t] = f2bf(v - bf2f(hi));
}

__device__ __forceinline__ void pack_one(const float* __restrict__ W,
                                         short* __restrict__ Ph, short* __restrict__ Pl,
                                         int K, int J, int ld, int trans, int KS, int t) {
    int i    = t & 7;
    int lane = (t >> 3) & 63;
    int blk  = t >> 9;
    int ks = blk % KS, ct = blk / KS;
    int j = ct * 16 + (lane & 15);
    int k = ks * 32 + ((lane >> 4) << 3) + i;
    float v = 0.f;
    if (j < J && k < K) v = trans ? W[(long)j * ld + k] : W[(long)k * ld + j];
    short hi = f2bf(v);
    Ph[t] = hi;
    Pl[t] = f2bf(v - bf2f(hi));
}

__global__ void k_packall(const float* __restrict__ W_hh, const float* __restrict__ W_ih,
                          const float* __restrict__ W1, const float* __restrict__ W2,
                          short* __restrict__ Bhi, short* __restrict__ Blo,
                          short* __restrict__ PihH, short* __restrict__ PihL,
                          short* __restrict__ P1H, short* __restrict__ P1L,
                          short* __restrict__ P2H, short* __restrict__ P2L) {
    int t = blockIdx.x * blockDim.x + threadIdx.x;
    if (t < 43008) { bpack_one(W_hh, Bhi, Blo, t); return; }
    t -= 43008;
    if (t < 38912) { pack_one(W_ih, PihH, PihL, 100, 300, 100, 1, 4, t); return; }
    t -= 38912;
    if (t < 14336) { pack_one(W1, P1H, P1L, 100, 100, 100, 0, 4, t); return; }
    t -= 14336;
    if (t < 25088) { pack_one(W2, P2H, P2L, 200, 100, 100, 0, 7, t); return; }
}

// ---------------------------------------------------------------------------
// Generic MFMA GEMM: out[n, j] = sum_k A[n,k]*B[k,j] (+ bias[j]).
// Staging vectorized: float4 global loads + short4 LDS writes (K % 4 == 0).
// ileave=1: write in GRU-interleaved layout off = row*300 + (j%100)*3 + j/100.
// ---------------------------------------------------------------------------
template <int KS>
__global__ __launch_bounds__(448) void k_gemm(
        const float* __restrict__ A, int K, int nrows,
        const short* __restrict__ Bh, const short* __restrict__ Bl,
        const float* __restrict__ bias, float* __restrict__ out, int ldo,
        int J, int CT, int ileave) {
    constexpr int Kp  = KS * 32;
    constexpr int C4  = Kp / 4;
    constexpr int STR = Kp + 8;                 // shorts per staged row
    __shared__ short sA[2][64 * STR];           // [hi/lo][row*STR + k]

    const int tid  = threadIdx.x;
    const int w    = tid >> 6;
    const int lane = tid & 63;
    const int n0   = lane & 15;
    const int q    = lane >> 4;
    const int row0 = blockIdx.x * 64;

    const int K4 = K / 4;
    for (int idx = tid; idx < 64 * C4; idx += 448) {
        int nd = idx / C4, c4 = idx % C4;
        int r = row0 + nd; if (r >= nrows) r = nrows - 1;
        float4 v = {0.f, 0.f, 0.f, 0.f};
        if (c4 < K4) v = *(const float4*)&A[(long)r * K + 4 * c4];
        s16x4 hi, lo;
        hi.x = f2bf(v.x); lo.x = f2bf(v.x - bf2f(hi.x));
        hi.y = f2bf(v.y); lo.y = f2bf(v.y - bf2f(hi.y));
        hi.z = f2bf(v.z); lo.z = f2bf(v.z - bf2f(hi.z));
        hi.w = f2bf(v.w); lo.w = f2bf(v.w - bf2f(hi.w));
        *(s16x4*)&sA[0][nd * STR + 4 * c4] = hi;
        *(s16x4*)&sA[1][nd * STR + 4 * c4] = lo;
    }
    __syncthreads();

    for (int ct = w; ct < CT; ct += 7) {
        bf16x8 bh[KS], bl[KS];
#pragma unroll
        for (int ks = 0; ks < KS; ++ks) {
            long bo = ((long)(ct * KS + ks) * 64 + lane) * 8;
            bh[ks] = *(const bf16x8*)&Bh[bo];
            bl[ks] = *(const bf16x8*)&Bl[bo];
        }
        const int j = ct * 16 + n0;
        const bool jv = (j < J);
        const float bv = (bias != nullptr && jv) ? bias[j] : 0.f;
        const long obase = ileave ? ((long)(j % 100) * 3 + (j / 100)) : (long)j;

#pragma unroll
        for (int t = 0; t < 4; ++t) {
            f32x4 acc = (f32x4){0.f, 0.f, 0.f, 0.f};
#pragma unroll
            for (int ks = 0; ks < KS; ++ks) {
                int off = (t * 16 + n0) * STR + ks * 32 + q * 8;
                bf16x8 aHi = *(const bf16x8*)&sA[0][off];
                bf16x8 aLo = *(const bf16x8*)&sA[1][off];
                acc = __builtin_amdgcn_mfma_f32_16x16x32_bf16(aHi, bh[ks], acc, 0, 0, 0);
                acc = __builtin_amdgcn_mfma_f32_16x16x32_bf16(aHi, bl[ks], acc, 0, 0, 0);
                acc = __builtin_amdgcn_mfma_f32_16x16x32_bf16(aLo, bh[ks], acc, 0, 0, 0);
            }
            if (jv) {
#pragma unroll
                for (int r = 0; r < 4; ++r) {
                    int row = row0 + t * 16 + 4 * q + r;
                    if (row < nrows) out[(long)row * ldo + obase] = acc[r] + bv;
                }
            }
        }
    }
}

// ---------------------------------------------------------------------------
// Conv2 GEMM with fused concat staging: A row r = relu([xc1[r], hn[idx[r]]]),
// K=200 (Kp=224). float4 staging.
// ---------------------------------------------------------------------------
__global__ __launch_bounds__(448) void k_gemm_cat(
        const float* __restrict__ xc1, const float* __restrict__ hn,
        const int* __restrict__ idx, int nrows,
        const short* __restrict__ Bh, const short* __restrict__ Bl,
        float* __restrict__ out, int CT) {
    constexpr int KS = 7, Kp = 224, STR = 232, C4 = 56;
    __shared__ short sA[2][64 * STR];

    const int tid  = threadIdx.x;
    const int w    = tid >> 6;
    const int lane = tid & 63;
    const int n0   = lane & 15;
    const int q    = lane >> 4;
    const int row0 = blockIdx.x * 64;

    for (int t = tid; t < 64 * C4; t += 448) {
        int nd = t / C4, c4 = t % C4;
        int r = row0 + nd; if (r >= nrows) r = nrows - 1;
        float4 v = {0.f, 0.f, 0.f, 0.f};
        if (c4 < 25)      v = *(const float4*)&xc1[(long)r * 100 + 4 * c4];
        else if (c4 < 50) v = *(const float4*)&hn[(long)idx[r] * 100 + 4 * (c4 - 25)];
        v.x = fmaxf(v.x, 0.f); v.y = fmaxf(v.y, 0.f);
        v.z = fmaxf(v.z, 0.f); v.w = fmaxf(v.w, 0.f);
        s16x4 hi, lo;
        hi.x = f2bf(v.x); lo.x = f2bf(v.x - bf2f(hi.x));
        hi.y = f2bf(v.y); lo.y = f2bf(v.y - bf2f(hi.y));
        hi.z = f2bf(v.z); lo.z = f2bf(v.z - bf2f(hi.z));
        hi.w = f2bf(v.w); lo.w = f2bf(v.w - bf2f(hi.w));
        *(s16x4*)&sA[0][nd * STR + 4 * c4] = hi;
        *(s16x4*)&sA[1][nd * STR + 4 * c4] = lo;
    }
    __syncthreads();

    for (int ct = w; ct < CT; ct += 7) {
        bf16x8 bh[KS], bl[KS];
#pragma unroll
        for (int ks = 0; ks < KS; ++ks) {
            long bo = ((long)(ct * KS + ks) * 64 + lane) * 8;
            bh[ks] = *(const bf16x8*)&Bh[bo];
            bl[ks] = *(const bf16x8*)&Bl[bo];
        }
        const int j = ct * 16 + n0;
        const bool jv = (j < 100);

#pragma unroll
        for (int t4 = 0; t4 < 4; ++t4) {
            f32x4 acc = (f32x4){0.f, 0.f, 0.f, 0.f};
#pragma unroll
            for (int ks = 0; ks < KS; ++ks) {
                int off = (t4 * 16 + n0) * STR + ks * 32 + q * 8;
                bf16x8 aHi = *(const bf16x8*)&sA[0][off];
                bf16x8 aLo = *(const bf16x8*)&sA[1][off];
                acc = __builtin_amdgcn_mfma_f32_16x16x32_bf16(aHi, bh[ks], acc, 0, 0, 0);
                acc = __builtin_amdgcn_mfma_f32_16x16x32_bf16(aHi, bl[ks], acc, 0, 0, 0);
                acc = __builtin_amdgcn_mfma_f32_16x16x32_bf16(aLo, bh[ks], acc, 0, 0, 0);
            }
            if (jv) {
#pragma unroll
                for (int r = 0; r < 4; ++r) {
                    int row = row0 + t4 * 16 + 4 * q + r;
                    if (row < nrows) out[(long)row * 100 + j] = acc[r];
                }
            }
        }
    }
}

// ---------------------------------------------------------------------------
// MFMA GRU, round 10: 3 tiles/block, single barrier/step. Step reordered to
// [wx issue x3 + tok-next] -> MFMA(t0) -> MFMA(t1) -> epi0 -> MFMA(t2)
// -> epi1 -> epi2 -> barrier: tile-0's wx (Wemb is 60MB -> ~HBM latency)
// now has ~800cyc of MFMA cover instead of ~350 (the barrier-visible stall).
// Peak live acc = 2 tiles (24 AGPR, +12); watch WRITE_SIZE for spill.
// ---------------------------------------------------------------------------
__global__ __launch_bounds__(448, 2) void k_gru_mfma(
        const int* __restrict__ tok, const float* __restrict__ h0,
        const float* __restrict__ Wemb, const short* __restrict__ Bhi,
        const short* __restrict__ Blo, const float* __restrict__ b_hh,
        float* __restrict__ hout, int n_nodes) {
    __shared__ short hA[2][2][48 * 136];   // [buf][hi/lo][node*136+k], 52224B

    const int tid  = threadIdx.x;
    const int w    = tid >> 6;
    const int lane = tid & 63;
    const int n0   = lane & 15;
    const int q    = lane >> 4;
    const int node0 = blockIdx.x * 48;

    // ---- B fragments: 3 gates x 4 k-steps, hi+lo, loaded once ----
    bf16x8 bh[3][4], bl[3][4];
#pragma unroll
    for (int g = 0; g < 3; ++g)
#pragma unroll
        for (int ks = 0; ks < 4; ++ks) {
            long bo = ((long)((g * 7 + w) * 4 + ks) * 64 + lane) * 8;
            bh[g][ks] = *(const bf16x8*)&Bhi[bo];
            bl[g][ks] = *(const bf16x8*)&Blo[bo];
        }

    // ---- init h tables; buffer 1 zeroed so its k-pad (100..127) is 0 ----
    for (int i = tid; i < 48 * 128; i += 448) {
        int nd = i >> 7, c = i & 127;
        int row = node0 + nd; if (row >= n_nodes) row = n_nodes - 1;
        float v = (c < 100) ? h0[(long)row * 100 + c] : 0.f;
        short hi = f2bf(v);
        hA[0][0][nd * 136 + c] = hi;
        hA[0][1][nd * 136 + c] = f2bf(v - bf2f(hi));
        hA[1][0][nd * 136 + c] = 0;
        hA[1][1][nd * 136 + c] = 0;
    }

    const int j   = 16 * w + n0;
    const int jc  = j < 100 ? j : 99;
    const bool jok = (j < 100);
    const float bhr = b_hh[jc], bhz = b_hh[100 + jc], bhn = b_hh[200 + jc];

    // token-row bases (rows*SEQL precomputed; rows not kept)
    long rl0[4], rl1[4], rl2[4];
    float hp0[4], hp1[4], hp2[4];
#pragma unroll
    for (int r = 0; r < 4; ++r) {
        int a0 = node0 + 4 * q + r;
        int a1 = a0 + 16;
        int a2 = a0 + 32;
        a0 = a0 < n_nodes ? a0 : n_nodes - 1;
        a1 = a1 < n_nodes ? a1 : n_nodes - 1;
        a2 = a2 < n_nodes ? a2 : n_nodes - 1;
        rl0[r] = (long)a0 * SEQL; rl1[r] = (long)a1 * SEQL; rl2[r] = (long)a2 * SEQL;
        hp0[r] = h0[(long)a0 * 100 + jc];
        hp1[r] = h0[(long)a1 * 100 + jc];
        hp2[r] = h0[(long)a2 * 100 + jc];
    }

    __syncthreads();

    int tb0[4], tb1[4], tb2[4];
#pragma unroll
    for (int r = 0; r < 4; ++r) tb0[r] = tok[rl0[r]] * 300;
#pragma unroll
    for (int r = 0; r < 4; ++r) tb1[r] = tok[rl1[r]] * 300;
#pragma unroll
    for (int r = 0; r < 4; ++r) tb2[r] = tok[rl2[r]] * 300;

    const int jc3 = 3 * jc;

    int cur = 0;
#pragma unroll 1
    for (int l = 0; l < SEQL; ++l) {
        // ---- issue ALL wx gathers + next-step token loads first ----
        float wxA[12], wxB[12], wxC[12];
#pragma unroll
        for (int r = 0; r < 4; ++r) {
            const float* p = Wemb + (long)tb0[r] + jc3;
            wxA[r] = p[0]; wxA[4 + r] = p[1]; wxA[8 + r] = p[2];
        }
#pragma unroll
        for (int r = 0; r < 4; ++r) {
            const float* p = Wemb + (long)tb1[r] + jc3;
            wxB[r] = p[0]; wxB[4 + r] = p[1]; wxB[8 + r] = p[2];
        }
#pragma unroll
        for (int r = 0; r < 4; ++r) {
            const float* p = Wemb + (long)tb2[r] + jc3;
            wxC[r] = p[0]; wxC[4 + r] = p[1]; wxC[8 + r] = p[2];
        }
        int tnx[4], tny[4], tnz[4];
        if (l < SEQL - 1) {
#pragma unroll
            for (int r = 0; r < 4; ++r) tnx[r] = tok[rl0[r] + l + 1] * 300;
#pragma unroll
            for (int r = 0; r < 4; ++r) tny[r] = tok[rl1[r] + l + 1] * 300;
#pragma unroll
            for (int r = 0; r < 4; ++r) tnz[r] = tok[rl2[r] + l + 1] * 300;
        }

        const short* hc0 = &hA[cur][0][0];
        const short* hc1 = &hA[cur][1][0];
        short* hn0 = &hA[cur ^ 1][0][0];
        short* hn1 = &hA[cur ^ 1][1][0];

        auto epi = [&](const float* wx, float* hp, int ndo, const f32x4* acc) {
#pragma unroll
            for (int r = 0; r < 4; ++r) {
                float pr = wx[r]     + acc[0][r] + bhr;
                float pz = wx[4 + r] + acc[1][r] + bhz;
                float rr = __builtin_amdgcn_rcpf(1.f + __expf(-pr));
                float zz = __builtin_amdgcn_rcpf(1.f + __expf(-pz));
                float pn = wx[8 + r] + rr * (acc[2][r] + bhn);
                float th = 1.f - 2.f * __builtin_amdgcn_rcpf(1.f + __expf(2.f * pn));
                float hnew = (1.f - zz) * th + zz * hp[r];
                hp[r] = hnew;
                if (jok) {
                    int off = (ndo + 4 * q + r) * 136 + j;
                    short hi = f2bf(hnew);
                    hn0[off] = hi;
                    hn1[off] = f2bf(hnew - bf2f(hi));
                }
            }
        };
        auto mfma_tile = [&](int ndo, f32x4* acc) {
            bf16x8 aHi[4], aLo[4];
#pragma unroll
            for (int ks = 0; ks < 4; ++ks) {
                int off = (ndo + n0) * 136 + ks * 32 + q * 8;
                aHi[ks] = *(const bf16x8*)&hc0[off];
                aLo[ks] = *(const bf16x8*)&hc1[off];
            }
#pragma unroll
            for (int g = 0; g < 3; ++g) acc[g] = (f32x4){0.f, 0.f, 0.f, 0.f};
#pragma unroll
            for (int g = 0; g < 3; ++g)
#pragma unroll
                for (int ks = 0; ks < 4; ++ks) {
                    acc[g] = __builtin_amdgcn_mfma_f32_16x16x32_bf16(aHi[ks], bh[g][ks], acc[g], 0, 0, 0);
                    acc[g] = __builtin_amdgcn_mfma_f32_16x16x32_bf16(aHi[ks], bl[g][ks], acc[g], 0, 0, 0);
                    acc[g] = __builtin_amdgcn_mfma_f32_16x16x32_bf16(aLo[ks], bh[g][ks], acc[g], 0, 0, 0);
                }
        };

        f32x4 acc0[3], acc1[3], acc2[3];
        mfma_tile(0, acc0);
        mfma_tile(16, acc1);
        epi(wxA, hp0, 0, acc0);
        mfma_tile(32, acc2);
        epi(wxB, hp1, 16, acc1);
        epi(wxC, hp2, 32, acc2);

        if (l < SEQL - 1) {
#pragma unroll
            for (int r = 0; r < 4; ++r) { tb0[r] = tnx[r]; tb1[r] = tny[r]; tb2[r] = tnz[r]; }
        }
        __syncthreads();
        cur ^= 1;
    }

    for (int i = tid; i < 48 * 100; i += 448) {
        int nd = i / 100, c = i % 100;
        if (node0 + nd < n_nodes)
            hout[(long)(node0 + nd) * 100 + c] =
                bf2f(hA[cur][0][nd * 136 + c]) + bf2f(hA[cur][1][nd * 136 + c]);
    }
}

// ---------------------------------------------------------------------------
// Degree (int atomics)
// ---------------------------------------------------------------------------
__global__ void k_deg(const int* __restrict__ dst, int* __restrict__ degi, int E) {
    int e = blockIdx.x * blockDim.x + threadIdx.x;
    if (e < E) atomicAdd(&degi[dst[e]], 1);
}

// ---------------------------------------------------------------------------
// Parallel scan: per-block sums -> exclusive scan of partials -> emit.
// ---------------------------------------------------------------------------
__global__ __launch_bounds__(256) void k_scan_bsum(const int* __restrict__ degi,
                                                   int* __restrict__ bsum, int N) {
    __shared__ int sh[256];
    int t = threadIdx.x, i = blockIdx.x * 256 + t;
    sh[t] = (i < N) ? degi[i] : 0;
    __syncthreads();
    for (int o = 128; o > 0; o >>= 1) {
        if (t < o) sh[t] += sh[t + o];
        __syncthreads();
    }
    if (t == 0) bsum[blockIdx.x] = sh[0];
}

__global__ __launch_bounds__(1024) void k_scan_part(int* __restrict__ bsum, int G) {
    __shared__ int sh[1024];
    int t = threadIdx.x;
    int v = (t < G) ? bsum[t] : 0;
    sh[t] = v;
    __syncthreads();
    for (int o = 1; o < 1024; o <<= 1) {
        int a = (t >= o) ? sh[t - o] : 0;
        __syncthreads();
        sh[t] += a;
        __syncthreads();
    }
    if (t < G) bsum[t] = sh[t] - v;   // exclusive
}

__global__ __launch_bounds__(256) void k_scan_emit(const int* __restrict__ degi,
                                                   const int* __restrict__ bsum,
                                                   int* __restrict__ rs, int* __restrict__ cursor,
                                                   float* __restrict__ dinv, int N, int E) {
    __shared__ int sh[256];
    int t = threadIdx.x, i = blockIdx.x * 256 + t;
    int d = (i < N) ? degi[i] : 0;
    sh[t] = d;
    __syncthreads();
    for (int o = 1; o < 256; o <<= 1) {
        int a = (t >= o) ? sh[t - o] : 0;
        __syncthreads();
        sh[t] += a;
        __syncthreads();
    }
    if (i < N) {
        int run = bsum[blockIdx.x] + sh[t] - d;
        rs[i] = run;
        cursor[i] = run;
        dinv[i] = rsqrtf((float)d + 1.0f);
        if (i == N - 1) rs[N] = E;
    }
}

// ---------------------------------------------------------------------------
// Scatter edges into CSR order (by dst)
// ---------------------------------------------------------------------------
__global__ void k_scatter(const int* __restrict__ src, const int* __restrict__ dst,
                          int* __restrict__ cursor, int* __restrict__ esrc, int E) {
    int e = blockIdx.x * blockDim.x + threadIdx.x;
    if (e >= E) return;
    int pos = atomicAdd(&cursor[dst[e]], 1);
    esrc[pos] = src[e];
}

// ---------------------------------------------------------------------------
// Conv1 finish: CSR gather (no atomics) + self term + bias -> xc1 (pre-relu).
// ---------------------------------------------------------------------------
__global__ void k_conv1_fin(const int* __restrict__ rs, const int* __restrict__ esrc,
                            const float* __restrict__ xw, const float* __restrict__ dinv,
                            const float* __restrict__ b1, float* __restrict__ xc1, int N) {
    int t = blockIdx.x * blockDim.x + threadIdx.x;
    if (t >= N * 25) return;
    int n = t / 25, jq = t % 25;
    float dn = dinv[n];
    float4 acc = {0.f, 0.f, 0.f, 0.f};
    int e1 = rs[n + 1];
    for (int e = rs[n]; e < e1; ++e) {
        int s = esrc[e];
        float ds = dinv[s];
        float4 xs = ((const float4*)xw)[s * 25 + jq];
        acc.x = fmaf(xs.x, ds, acc.x);
        acc.y = fmaf(xs.y, ds, acc.y);
        acc.z = fmaf(xs.z, ds, acc.z);
        acc.w = fmaf(xs.w, ds, acc.w);
    }
    float4 xs = ((const float4*)xw)[t];
    float4 bq = ((const float4*)b1)[jq];
    float dn2 = dn * dn;
    float4 v;
    v.x = fmaf(acc.x, dn, fmaf(xs.x, dn2, bq.x));
    v.y = fmaf(acc.y, dn, fmaf(xs.y, dn2, bq.y));
    v.z = fmaf(acc.z, dn, fmaf(xs.z, dn2, bq.z));
    v.w = fmaf(acc.w, dn, fmaf(xs.w, dn2, bq.w));
    ((float4*)xc1)[t] = v;
}

// ---------------------------------------------------------------------------
// Conv2 finish: out = [relu(agg2 + self + b2), xc1[idx]]
// ---------------------------------------------------------------------------
__global__ void k_conv2_fin(const int* __restrict__ rs, const int* __restrict__ esrc,
                            const float* __restrict__ xw, const float* __restrict__ dinv,
                            const float* __restrict__ b2, const float* __restrict__ xc1,
                            const int* __restrict__ idx, float* __restrict__ out, int N) {
    int t = blockIdx.x * blockDim.x + threadIdx.x;
    if (t >= N * 25) return;
    int n = t / 25, jq = t % 25;
    float dn = dinv[n];
    float4 acc = {0.f, 0.f, 0.f, 0.f};
    int e1 = rs[n + 1];
    for (int e = rs[n]; e < e1; ++e) {
        int s = esrc[e];
        float ds = dinv[s];
        float4 xs = ((const float4*)xw)[s * 25 + jq];
        acc.x = fmaf(xs.x, ds, acc.x);
        acc.y = fmaf(xs.y, ds, acc.y);
        acc.z = fmaf(xs.z, ds, acc.z);
        acc.w = fmaf(xs.w, ds, acc.w);
    }
    float4 xs = ((const float4*)xw)[t];
    float4 bq = ((const float4*)b2)[jq];
    float dn2 = dn * dn;
    float4 v;
    v.x = fmaxf(fmaf(acc.x, dn, fmaf(xs.x, dn2, bq.x)), 0.f);
    v.y = fmaxf(fmaf(acc.y, dn, fmaf(xs.y, dn2, bq.y)), 0.f);
    v.z = fmaxf(fmaf(acc.z, dn, fmaf(xs.z, dn2, bq.z)), 0.f);
    v.w = fmaxf(fmaf(acc.w, dn, fmaf(xs.w, dn2, bq.w)), 0.f);
    float4 rv = ((const float4*)xc1)[(long)idx[n] * 25 + jq];
    ((float4*)out)[n * 50 + jq] = v;
    ((float4*)out)[n * 50 + 25 + jq] = rv;
}

// ---------------------------------------------------------------------------
extern "C" void kernel_launch(void* const* d_in, const int* in_sizes, int n_in,
                              void* d_out, int out_size, void* d_ws, size_t ws_size,
                              hipStream_t stream) {
    const int*   feat    = (const int*)d_in[0];
    const int*   edges   = (const int*)d_in[1];
    const int*   indices = (const int*)d_in[2];
    const float* h0      = (const float*)d_in[3];
    const float* emb     = (const float*)d_in[4];
    const float* W_ih    = (const float*)d_in[5];
    const float* W_hh    = (const float*)d_in[6];
    const float* b_ih    = (const float*)d_in[7];
    const float* b_hh    = (const float*)d_in[8];
    const float* W1      = (const float*)d_in[9];
    const float* b1      = (const float*)d_in[10];
    const float* W2      = (const float*)d_in[11];
    const float* b2      = (const float*)d_in[12];
    float* out = (float*)d_out;

    const int N = in_sizes[2];
    const int E = in_sizes[1] / 2;
    const int V = in_sizes[4] / D_IN;
    const int* src = edges;
    const int* dst = edges + E;

    float* ws   = (float*)d_ws;
    float* hbuf = ws;                         // N*100
    float* Wemb = hbuf + (long)N * H;         // V*300 (reused as xw after GRU)
    float* xw   = Wemb;                       // reuse: N*100
    float* xc1  = Wemb + (long)V * 300;       // N*100
    float* xbig = xc1 + (long)N * 100;        // N*200 (unused; kept for layout)
    float* dinv = xbig + (long)N * 200;       // N
    short* Bhi  = (short*)(dinv + N);         // 43008 bf16 (GRU W_hh)
    short* Blo  = Bhi + 43008;                // 43008
    short* PihH = Blo + 43008;                // 38912 (W_ih: CT=19, KS=4)
    short* PihL = PihH + 38912;               // 38912
    short* P1H  = PihL + 38912;               // 14336 (W1: CT=7, KS=4)
    short* P1L  = P1H + 14336;                // 14336
    short* P2H  = P1L + 14336;                // 25088 (W2: CT=7, KS=7)
    short* P2L  = P2H + 25088;                // 25088
    int*   degi = (int*)(P2L + 25088);        // N
    int*   rs   = degi + N;                   // N+1
    int*   cursor = rs + N + 1;               // N
    int*   esrc = cursor + N;                 // E
    int*   bsum = esrc + E;                   // ceil(N/256) partials
    (void)ws_size; (void)n_in; (void)out_size;

    const int B = 256;
    const int Gs = (N + 255) / 256;

    hipMemsetAsync(degi, 0, (size_t)N * sizeof(int), stream);
    k_deg<<<(E + B - 1) / B, B, 0, stream>>>(dst, degi, E);
    k_scan_bsum<<<Gs, 256, 0, stream>>>(degi, bsum, N);
    k_scan_part<<<1, 1024, 0, stream>>>(bsum, Gs);
    k_scan_emit<<<Gs, 256, 0, stream>>>(degi, bsum, rs, cursor, dinv, N, E);
    k_scatter<<<(E + B - 1) / B, B, 0, stream>>>(src, dst, cursor, esrc, E);

    k_packall<<<(121344 + B - 1) / B, B, 0, stream>>>(W_hh, W_ih, W1, W2,
                                                      Bhi, Blo, PihH, PihL,
                                                      P1H, P1L, P2H, P2L);

    // Wemb = emb @ W_ih^T + b_ih, interleaved [v][jc][g]
    k_gemm<4><<<(V + 63) / 64, 448, 0, stream>>>(emb, 100, V, PihH, PihL, b_ih,
                                                 Wemb, 300, 300, 19, 1);

    k_gru_mfma<<<(N + 47) / 48, 448, 0, stream>>>(feat, h0, Wemb, Bhi, Blo, b_hh, hbuf, N);

    {
        // xw = hbuf @ W1
        k_gemm<4><<<(N + 63) / 64, 448, 0, stream>>>(hbuf, 100, N, P1H, P1L, nullptr,
                                                     xw, 100, 100, 7, 0);
        int nquads = N * 25;
        k_conv1_fin<<<(nquads + B - 1) / B, B, 0, stream>>>(rs, esrc, xw, dinv, b1, xc1, N);
        // xw = relu([xc1, hn[idx]]) @ W2  (concat staged in-kernel)
        k_gemm_cat<<<(N + 63) / 64, 448, 0, stream>>>(xc1, hbuf, indices, N,
                                                      P2H, P2L, xw, 7);
        k_conv2_fin<<<(nquads + B - 1) / B, B, 0, stream>>>(rs, esrc, xw, dinv, b2, xc1,
                                                            indices, out, N);
    }
}

// Round 6
// 906.249 us; speedup vs baseline: 1.1945x; 1.1945x over previous
//
#include <hip/hip_runtime.h>
#include <math.h>

#define D_IN 100
#define H    100
#define SEQL 30

typedef __attribute__((ext_vector_type(8))) short bf16x8;
typedef __attribute__((ext_vector_type(4))) short s16x4;
typedef __attribute__((ext_vector_type(4))) float f32x4;

__device__ __forceinline__ short f2bf(float f) {
    unsigned u = __builtin_bit_cast(unsigned, f);
    unsigned r = (u + 0x7FFFu + ((u >> 16) & 1u)) >> 16;
    return (short)r;
}
__device__ __forceinline__ float bf2f(short s) {
    unsigned u = ((unsigned)(unsigned short)s) << 16;
    return __builtin_bit_cast(float, u);
}

// ---------------------------------------------------------------------------
// Fused weight packing (one launch instead of four).
// ---------------------------------------------------------------------------
__device__ __forceinline__ void bpack_one(const float* __restrict__ W_hh,
                                          short* __restrict__ Bhi,
                                          short* __restrict__ Blo, int t) {
    int i    = t & 7;
    int lane = (t >> 3) & 63;
    int blk  = t >> 9;            // nt*4 + ks
    int ks = blk & 3, nt = blk >> 2;
    int np = nt * 16 + (lane & 15);
    int k  = ks * 32 + ((lane >> 4) << 3) + i;
    int g = np / 112, j = np % 112;
    float v = (j < 100 && k < 100) ? W_hh[(g * 100 + j) * 100 + k] : 0.f;
    short hi = f2bf(v);
    Bhi[t] = hi;
    Blo[t] = f2bf(v - bf2f(hi));
}

__device__ __forceinline__ void pack_one(const float* __restrict__ W,
                                         short* __restrict__ Ph, short* __restrict__ Pl,
                                         int K, int J, int ld, int trans, int KS, int t) {
    int i    = t & 7;
    int lane = (t >> 3) & 63;
    int blk  = t >> 9;
    int ks = blk % KS, ct = blk / KS;
    int j = ct * 16 + (lane & 15);
    int k = ks * 32 + ((lane >> 4) << 3) + i;
    float v = 0.f;
    if (j < J && k < K) v = trans ? W[(long)j * ld + k] : W[(long)k * ld + j];
    short hi = f2bf(v);
    Ph[t] = hi;
    Pl[t] = f2bf(v - bf2f(hi));
}

__global__ void k_packall(const float* __restrict__ W_hh, const float* __restrict__ W_ih,
                          const float* __restrict__ W1, const float* __restrict__ W2,
                          short* __restrict__ Bhi, short* __restrict__ Blo,
                          short* __restrict__ PihH, short* __restrict__ PihL,
                          short* __restrict__ P1H, short* __restrict__ P1L,
                          short* __restrict__ P2H, short* __restrict__ P2L) {
    int t = blockIdx.x * blockDim.x + threadIdx.x;
    if (t < 43008) { bpack_one(W_hh, Bhi, Blo, t); return; }
    t -= 43008;
    if (t < 38912) { pack_one(W_ih, PihH, PihL, 100, 300, 100, 1, 4, t); return; }
    t -= 38912;
    if (t < 14336) { pack_one(W1, P1H, P1L, 100, 100, 100, 0, 4, t); return; }
    t -= 14336;
    if (t < 25088) { pack_one(W2, P2H, P2L, 200, 100, 100, 0, 7, t); return; }
}

// ---------------------------------------------------------------------------
// Generic MFMA GEMM: out[n, j] = sum_k A[n,k]*B[k,j] (+ bias[j]).
// Staging vectorized: float4 global loads + short4 LDS writes (K % 4 == 0).
// ileave=1: write in GRU-interleaved layout off = row*300 + (j%100)*3 + j/100.
// ---------------------------------------------------------------------------
template <int KS>
__global__ __launch_bounds__(448) void k_gemm(
        const float* __restrict__ A, int K, int nrows,
        const short* __restrict__ Bh, const short* __restrict__ Bl,
        const float* __restrict__ bias, float* __restrict__ out, int ldo,
        int J, int CT, int ileave) {
    constexpr int Kp  = KS * 32;
    constexpr int C4  = Kp / 4;
    constexpr int STR = Kp + 8;                 // shorts per staged row
    __shared__ short sA[2][64 * STR];           // [hi/lo][row*STR + k]

    const int tid  = threadIdx.x;
    const int w    = tid >> 6;
    const int lane = tid & 63;
    const int n0   = lane & 15;
    const int q    = lane >> 4;
    const int row0 = blockIdx.x * 64;

    const int K4 = K / 4;
    for (int idx = tid; idx < 64 * C4; idx += 448) {
        int nd = idx / C4, c4 = idx % C4;
        int r = row0 + nd; if (r >= nrows) r = nrows - 1;
        float4 v = {0.f, 0.f, 0.f, 0.f};
        if (c4 < K4) v = *(const float4*)&A[(long)r * K + 4 * c4];
        s16x4 hi, lo;
        hi.x = f2bf(v.x); lo.x = f2bf(v.x - bf2f(hi.x));
        hi.y = f2bf(v.y); lo.y = f2bf(v.y - bf2f(hi.y));
        hi.z = f2bf(v.z); lo.z = f2bf(v.z - bf2f(hi.z));
        hi.w = f2bf(v.w); lo.w = f2bf(v.w - bf2f(hi.w));
        *(s16x4*)&sA[0][nd * STR + 4 * c4] = hi;
        *(s16x4*)&sA[1][nd * STR + 4 * c4] = lo;
    }
    __syncthreads();

    for (int ct = w; ct < CT; ct += 7) {
        bf16x8 bh[KS], bl[KS];
#pragma unroll
        for (int ks = 0; ks < KS; ++ks) {
            long bo = ((long)(ct * KS + ks) * 64 + lane) * 8;
            bh[ks] = *(const bf16x8*)&Bh[bo];
            bl[ks] = *(const bf16x8*)&Bl[bo];
        }
        const int j = ct * 16 + n0;
        const bool jv = (j < J);
        const float bv = (bias != nullptr && jv) ? bias[j] : 0.f;
        const long obase = ileave ? ((long)(j % 100) * 3 + (j / 100)) : (long)j;

#pragma unroll
        for (int t = 0; t < 4; ++t) {
            f32x4 acc = (f32x4){0.f, 0.f, 0.f, 0.f};
#pragma unroll
            for (int ks = 0; ks < KS; ++ks) {
                int off = (t * 16 + n0) * STR + ks * 32 + q * 8;
                bf16x8 aHi = *(const bf16x8*)&sA[0][off];
                bf16x8 aLo = *(const bf16x8*)&sA[1][off];
                acc = __builtin_amdgcn_mfma_f32_16x16x32_bf16(aHi, bh[ks], acc, 0, 0, 0);
                acc = __builtin_amdgcn_mfma_f32_16x16x32_bf16(aHi, bl[ks], acc, 0, 0, 0);
                acc = __builtin_amdgcn_mfma_f32_16x16x32_bf16(aLo, bh[ks], acc, 0, 0, 0);
            }
            if (jv) {
#pragma unroll
                for (int r = 0; r < 4; ++r) {
                    int row = row0 + t * 16 + 4 * q + r;
                    if (row < nrows) out[(long)row * ldo + obase] = acc[r] + bv;
                }
            }
        }
    }
}

// ---------------------------------------------------------------------------
// Conv2 GEMM with fused concat staging: A row r = relu([xc1[r], hn[idx[r]]]),
// K=200 (Kp=224). float4 staging.
// ---------------------------------------------------------------------------
__global__ __launch_bounds__(448) void k_gemm_cat(
        const float* __restrict__ xc1, const float* __restrict__ hn,
        const int* __restrict__ idx, int nrows,
        const short* __restrict__ Bh, const short* __restrict__ Bl,
        float* __restrict__ out, int CT) {
    constexpr int KS = 7, Kp = 224, STR = 232, C4 = 56;
    __shared__ short sA[2][64 * STR];

    const int tid  = threadIdx.x;
    const int w    = tid >> 6;
    const int lane = tid & 63;
    const int n0   = lane & 15;
    const int q    = lane >> 4;
    const int row0 = blockIdx.x * 64;

    for (int t = tid; t < 64 * C4; t += 448) {
        int nd = t / C4, c4 = t % C4;
        int r = row0 + nd; if (r >= nrows) r = nrows - 1;
        float4 v = {0.f, 0.f, 0.f, 0.f};
        if (c4 < 25)      v = *(const float4*)&xc1[(long)r * 100 + 4 * c4];
        else if (c4 < 50) v = *(const float4*)&hn[(long)idx[r] * 100 + 4 * (c4 - 25)];
        v.x = fmaxf(v.x, 0.f); v.y = fmaxf(v.y, 0.f);
        v.z = fmaxf(v.z, 0.f); v.w = fmaxf(v.w, 0.f);
        s16x4 hi, lo;
        hi.x = f2bf(v.x); lo.x = f2bf(v.x - bf2f(hi.x));
        hi.y = f2bf(v.y); lo.y = f2bf(v.y - bf2f(hi.y));
        hi.z = f2bf(v.z); lo.z = f2bf(v.z - bf2f(hi.z));
        hi.w = f2bf(v.w); lo.w = f2bf(v.w - bf2f(hi.w));
        *(s16x4*)&sA[0][nd * STR + 4 * c4] = hi;
        *(s16x4*)&sA[1][nd * STR + 4 * c4] = lo;
    }
    __syncthreads();

    for (int ct = w; ct < CT; ct += 7) {
        bf16x8 bh[KS], bl[KS];
#pragma unroll
        for (int ks = 0; ks < KS; ++ks) {
            long bo = ((long)(ct * KS + ks) * 64 + lane) * 8;
            bh[ks] = *(const bf16x8*)&Bh[bo];
            bl[ks] = *(const bf16x8*)&Bl[bo];
        }
        const int j = ct * 16 + n0;
        const bool jv = (j < 100);

#pragma unroll
        for (int t4 = 0; t4 < 4; ++t4) {
            f32x4 acc = (f32x4){0.f, 0.f, 0.f, 0.f};
#pragma unroll
            for (int ks = 0; ks < KS; ++ks) {
                int off = (t4 * 16 + n0) * STR + ks * 32 + q * 8;
                bf16x8 aHi = *(const bf16x8*)&sA[0][off];
                bf16x8 aLo = *(const bf16x8*)&sA[1][off];
                acc = __builtin_amdgcn_mfma_f32_16x16x32_bf16(aHi, bh[ks], acc, 0, 0, 0);
                acc = __builtin_amdgcn_mfma_f32_16x16x32_bf16(aHi, bl[ks], acc, 0, 0, 0);
                acc = __builtin_amdgcn_mfma_f32_16x16x32_bf16(aLo, bh[ks], acc, 0, 0, 0);
            }
            if (jv) {
#pragma unroll
                for (int r = 0; r < 4; ++r) {
                    int row = row0 + t4 * 16 + 4 * q + r;
                    if (row < nrows) out[(long)row * 100 + j] = acc[r];
                }
            }
        }
    }
}

// ---------------------------------------------------------------------------
// MFMA GRU — EXACT round-4 structure (651us, verified no-spill): 3 tiles per
// block, sequential per-tile {A-read, MFMA, epilogue} so only ONE acc set is
// live at a time. Round-5 lesson (twice confirmed): this kernel sits ~10 regs
// below the spill cliff; widening accumulator lifetimes (2 live acc sets)
// spills (WRITE_SIZE 23.4->49.7MB) and costs ~190us. Do not reorder.
// ---------------------------------------------------------------------------
__global__ __launch_bounds__(448, 2) void k_gru_mfma(
        const int* __restrict__ tok, const float* __restrict__ h0,
        const float* __restrict__ Wemb, const short* __restrict__ Bhi,
        const short* __restrict__ Blo, const float* __restrict__ b_hh,
        float* __restrict__ hout, int n_nodes) {
    __shared__ short hA[2][2][48 * 136];   // [buf][hi/lo][node*136+k], 52224B

    const int tid  = threadIdx.x;
    const int w    = tid >> 6;
    const int lane = tid & 63;
    const int n0   = lane & 15;
    const int q    = lane >> 4;
    const int node0 = blockIdx.x * 48;

    // ---- B fragments: 3 gates x 4 k-steps, hi+lo, loaded once ----
    bf16x8 bh[3][4], bl[3][4];
#pragma unroll
    for (int g = 0; g < 3; ++g)
#pragma unroll
        for (int ks = 0; ks < 4; ++ks) {
            long bo = ((long)((g * 7 + w) * 4 + ks) * 64 + lane) * 8;
            bh[g][ks] = *(const bf16x8*)&Bhi[bo];
            bl[g][ks] = *(const bf16x8*)&Blo[bo];
        }

    // ---- init h tables; buffer 1 zeroed so its k-pad (100..127) is 0 ----
    for (int i = tid; i < 48 * 128; i += 448) {
        int nd = i >> 7, c = i & 127;
        int row = node0 + nd; if (row >= n_nodes) row = n_nodes - 1;
        float v = (c < 100) ? h0[(long)row * 100 + c] : 0.f;
        short hi = f2bf(v);
        hA[0][0][nd * 136 + c] = hi;
        hA[0][1][nd * 136 + c] = f2bf(v - bf2f(hi));
        hA[1][0][nd * 136 + c] = 0;
        hA[1][1][nd * 136 + c] = 0;
    }

    const int j   = 16 * w + n0;
    const int jc  = j < 100 ? j : 99;
    const bool jok = (j < 100);
    const float bhr = b_hh[jc], bhz = b_hh[100 + jc], bhn = b_hh[200 + jc];

    int rows0[4], rows1[4], rows2[4];
#pragma unroll
    for (int r = 0; r < 4; ++r) {
        int a0 = node0 + 4 * q + r;
        int a1 = a0 + 16;
        int a2 = a0 + 32;
        rows0[r] = a0 < n_nodes ? a0 : n_nodes - 1;
        rows1[r] = a1 < n_nodes ? a1 : n_nodes - 1;
        rows2[r] = a2 < n_nodes ? a2 : n_nodes - 1;
    }
    float hp0[4], hp1[4], hp2[4];
#pragma unroll
    for (int r = 0; r < 4; ++r) hp0[r] = h0[(long)rows0[r] * 100 + jc];
#pragma unroll
    for (int r = 0; r < 4; ++r) hp1[r] = h0[(long)rows1[r] * 100 + jc];
#pragma unroll
    for (int r = 0; r < 4; ++r) hp2[r] = h0[(long)rows2[r] * 100 + jc];

    __syncthreads();

    int tb0[4], tb1[4], tb2[4];
#pragma unroll
    for (int r = 0; r < 4; ++r) tb0[r] = tok[(long)rows0[r] * SEQL] * 300;
#pragma unroll
    for (int r = 0; r < 4; ++r) tb1[r] = tok[(long)rows1[r] * SEQL] * 300;
#pragma unroll
    for (int r = 0; r < 4; ++r) tb2[r] = tok[(long)rows2[r] * SEQL] * 300;

    const int jc3 = 3 * jc;

    int cur = 0;
#pragma unroll 1
    for (int l = 0; l < SEQL; ++l) {
        // wx for tiles 0,1 issued first (consumed at their epilogues)
        float wxA[12], wxB[12];
#pragma unroll
        for (int r = 0; r < 4; ++r) {
            const float* p = Wemb + (long)tb0[r] + jc3;
            wxA[r] = p[0]; wxA[4 + r] = p[1]; wxA[8 + r] = p[2];
        }
#pragma unroll
        for (int r = 0; r < 4; ++r) {
            const float* p = Wemb + (long)tb1[r] + jc3;
            wxB[r] = p[0]; wxB[4 + r] = p[1]; wxB[8 + r] = p[2];
        }

        // next step's token bases
        int tnx[4], tny[4], tnz[4];
        if (l < SEQL - 1) {
#pragma unroll
            for (int r = 0; r < 4; ++r) tnx[r] = tok[(long)rows0[r] * SEQL + l + 1] * 300;
#pragma unroll
            for (int r = 0; r < 4; ++r) tny[r] = tok[(long)rows1[r] * SEQL + l + 1] * 300;
#pragma unroll
            for (int r = 0; r < 4; ++r) tnz[r] = tok[(long)rows2[r] * SEQL + l + 1] * 300;
        }

        const short* hc0 = &hA[cur][0][0];
        const short* hc1 = &hA[cur][1][0];
        short* hn0 = &hA[cur ^ 1][0][0];
        short* hn1 = &hA[cur ^ 1][1][0];

        f32x4 acc[3];
        auto epi = [&](const float* wx, float* hp, int ndo) {
#pragma unroll
            for (int r = 0; r < 4; ++r) {
                float pr = wx[r]     + acc[0][r] + bhr;
                float pz = wx[4 + r] + acc[1][r] + bhz;
                float rr = __builtin_amdgcn_rcpf(1.f + __expf(-pr));
                float zz = __builtin_amdgcn_rcpf(1.f + __expf(-pz));
                float pn = wx[8 + r] + rr * (acc[2][r] + bhn);
                float th = 1.f - 2.f * __builtin_amdgcn_rcpf(1.f + __expf(2.f * pn));
                float hnew = (1.f - zz) * th + zz * hp[r];
                hp[r] = hnew;
                if (jok) {
                    int off = (ndo + 4 * q + r) * 136 + j;
                    short hi = f2bf(hnew);
                    hn0[off] = hi;
                    hn1[off] = f2bf(hnew - bf2f(hi));
                }
            }
        };

        // ---- tile 0 ----
        {
            bf16x8 aHi[4], aLo[4];
#pragma unroll
            for (int ks = 0; ks < 4; ++ks) {
                int off = n0 * 136 + ks * 32 + q * 8;
                aHi[ks] = *(const bf16x8*)&hc0[off];
                aLo[ks] = *(const bf16x8*)&hc1[off];
            }
#pragma unroll
            for (int g = 0; g < 3; ++g) acc[g] = (f32x4){0.f, 0.f, 0.f, 0.f};
#pragma unroll
            for (int g = 0; g < 3; ++g)
#pragma unroll
                for (int ks = 0; ks < 4; ++ks) {
                    acc[g] = __builtin_amdgcn_mfma_f32_16x16x32_bf16(aHi[ks], bh[g][ks], acc[g], 0, 0, 0);
                    acc[g] = __builtin_amdgcn_mfma_f32_16x16x32_bf16(aHi[ks], bl[g][ks], acc[g], 0, 0, 0);
                    acc[g] = __builtin_amdgcn_mfma_f32_16x16x32_bf16(aLo[ks], bh[g][ks], acc[g], 0, 0, 0);
                }
            epi(wxA, hp0, 0);
        }

        // wx for tile 2 (covered by tile-1 MFMAs)
        float wxC[12];
#pragma unroll
        for (int r = 0; r < 4; ++r) {
            const float* p = Wemb + (long)tb2[r] + jc3;
            wxC[r] = p[0]; wxC[4 + r] = p[1]; wxC[8 + r] = p[2];
        }

        // ---- tile 1 ----
        {
            bf16x8 aHi[4], aLo[4];
#pragma unroll
            for (int ks = 0; ks < 4; ++ks) {
                int off = (16 + n0) * 136 + ks * 32 + q * 8;
                aHi[ks] = *(const bf16x8*)&hc0[off];
                aLo[ks] = *(const bf16x8*)&hc1[off];
            }
#pragma unroll
            for (int g = 0; g < 3; ++g) acc[g] = (f32x4){0.f, 0.f, 0.f, 0.f};
#pragma unroll
            for (int g = 0; g < 3; ++g)
#pragma unroll
                for (int ks = 0; ks < 4; ++ks) {
                    acc[g] = __builtin_amdgcn_mfma_f32_16x16x32_bf16(aHi[ks], bh[g][ks], acc[g], 0, 0, 0);
                    acc[g] = __builtin_amdgcn_mfma_f32_16x16x32_bf16(aHi[ks], bl[g][ks], acc[g], 0, 0, 0);
                    acc[g] = __builtin_amdgcn_mfma_f32_16x16x32_bf16(aLo[ks], bh[g][ks], acc[g], 0, 0, 0);
                }
            epi(wxB, hp1, 16);
        }

        // ---- tile 2 ----
        {
            bf16x8 aHi[4], aLo[4];
#pragma unroll
            for (int ks = 0; ks < 4; ++ks) {
                int off = (32 + n0) * 136 + ks * 32 + q * 8;
                aHi[ks] = *(const bf16x8*)&hc0[off];
                aLo[ks] = *(const bf16x8*)&hc1[off];
            }
#pragma unroll
            for (int g = 0; g < 3; ++g) acc[g] = (f32x4){0.f, 0.f, 0.f, 0.f};
#pragma unroll
            for (int g = 0; g < 3; ++g)
#pragma unroll
                for (int ks = 0; ks < 4; ++ks) {
                    acc[g] = __builtin_amdgcn_mfma_f32_16x16x32_bf16(aHi[ks], bh[g][ks], acc[g], 0, 0, 0);
                    acc[g] = __builtin_amdgcn_mfma_f32_16x16x32_bf16(aHi[ks], bl[g][ks], acc[g], 0, 0, 0);
                    acc[g] = __builtin_amdgcn_mfma_f32_16x16x32_bf16(aLo[ks], bh[g][ks], acc[g], 0, 0, 0);
                }
            epi(wxC, hp2, 32);
        }

        if (l < SEQL - 1) {
#pragma unroll
            for (int r = 0; r < 4; ++r) { tb0[r] = tnx[r]; tb1[r] = tny[r]; tb2[r] = tnz[r]; }
        }
        __syncthreads();
        cur ^= 1;
    }

    for (int i = tid; i < 48 * 100; i += 448) {
        int nd = i / 100, c = i % 100;
        if (node0 + nd < n_nodes)
            hout[(long)(node0 + nd) * 100 + c] =
                bf2f(hA[cur][0][nd * 136 + c]) + bf2f(hA[cur][1][nd * 136 + c]);
    }
}

// ---------------------------------------------------------------------------
// Degree (int atomics)
// ---------------------------------------------------------------------------
__global__ void k_deg(const int* __restrict__ dst, int* __restrict__ degi, int E) {
    int e = blockIdx.x * blockDim.x + threadIdx.x;
    if (e < E) atomicAdd(&degi[dst[e]], 1);
}

// ---------------------------------------------------------------------------
// Parallel scan: per-block sums -> exclusive scan of partials -> emit.
// ---------------------------------------------------------------------------
__global__ __launch_bounds__(256) void k_scan_bsum(const int* __restrict__ degi,
                                                   int* __restrict__ bsum, int N) {
    __shared__ int sh[256];
    int t = threadIdx.x, i = blockIdx.x * 256 + t;
    sh[t] = (i < N) ? degi[i] : 0;
    __syncthreads();
    for (int o = 128; o > 0; o >>= 1) {
        if (t < o) sh[t] += sh[t + o];
        __syncthreads();
    }
    if (t == 0) bsum[blockIdx.x] = sh[0];
}

__global__ __launch_bounds__(1024) void k_scan_part(int* __restrict__ bsum, int G) {
    __shared__ int sh[1024];
    int t = threadIdx.x;
    int v = (t < G) ? bsum[t] : 0;
    sh[t] = v;
    __syncthreads();
    for (int o = 1; o < 1024; o <<= 1) {
        int a = (t >= o) ? sh[t - o] : 0;
        __syncthreads();
        sh[t] += a;
        __syncthreads();
    }
    if (t < G) bsum[t] = sh[t] - v;   // exclusive
}

__global__ __launch_bounds__(256) void k_scan_emit(const int* __restrict__ degi,
                                                   const int* __restrict__ bsum,
                                                   int* __restrict__ rs, int* __restrict__ cursor,
                                                   float* __restrict__ dinv, int N, int E) {
    __shared__ int sh[256];
    int t = threadIdx.x, i = blockIdx.x * 256 + t;
    int d = (i < N) ? degi[i] : 0;
    sh[t] = d;
    __syncthreads();
    for (int o = 1; o < 256; o <<= 1) {
        int a = (t >= o) ? sh[t - o] : 0;
        __syncthreads();
        sh[t] += a;
        __syncthreads();
    }
    if (i < N) {
        int run = bsum[blockIdx.x] + sh[t] - d;
        rs[i] = run;
        cursor[i] = run;
        dinv[i] = rsqrtf((float)d + 1.0f);
        if (i == N - 1) rs[N] = E;
    }
}

// ---------------------------------------------------------------------------
// Scatter edges into CSR order (by dst)
// ---------------------------------------------------------------------------
__global__ void k_scatter(const int* __restrict__ src, const int* __restrict__ dst,
                          int* __restrict__ cursor, int* __restrict__ esrc, int E) {
    int e = blockIdx.x * blockDim.x + threadIdx.x;
    if (e >= E) return;
    int pos = atomicAdd(&cursor[dst[e]], 1);
    esrc[pos] = src[e];
}

// ---------------------------------------------------------------------------
// Conv1 finish: CSR gather (no atomics) + self term + bias -> xc1 (pre-relu).
// ---------------------------------------------------------------------------
__global__ void k_conv1_fin(const int* __restrict__ rs, const int* __restrict__ esrc,
                            const float* __restrict__ xw, const float* __restrict__ dinv,
                            const float* __restrict__ b1, float* __restrict__ xc1, int N) {
    int t = blockIdx.x * blockDim.x + threadIdx.x;
    if (t >= N * 25) return;
    int n = t / 25, jq = t % 25;
    float dn = dinv[n];
    float4 acc = {0.f, 0.f, 0.f, 0.f};
    int e1 = rs[n + 1];
    for (int e = rs[n]; e < e1; ++e) {
        int s = esrc[e];
        float ds = dinv[s];
        float4 xs = ((const float4*)xw)[s * 25 + jq];
        acc.x = fmaf(xs.x, ds, acc.x);
        acc.y = fmaf(xs.y, ds, acc.y);
        acc.z = fmaf(xs.z, ds, acc.z);
        acc.w = fmaf(xs.w, ds, acc.w);
    }
    float4 xs = ((const float4*)xw)[t];
    float4 bq = ((const float4*)b1)[jq];
    float dn2 = dn * dn;
    float4 v;
    v.x = fmaf(acc.x, dn, fmaf(xs.x, dn2, bq.x));
    v.y = fmaf(acc.y, dn, fmaf(xs.y, dn2, bq.y));
    v.z = fmaf(acc.z, dn, fmaf(xs.z, dn2, bq.z));
    v.w = fmaf(acc.w, dn, fmaf(xs.w, dn2, bq.w));
    ((float4*)xc1)[t] = v;
}

// ---------------------------------------------------------------------------
// Conv2 finish: out = [relu(agg2 + self + b2), xc1[idx]]
// ---------------------------------------------------------------------------
__global__ void k_conv2_fin(const int* __restrict__ rs, const int* __restrict__ esrc,
                            const float* __restrict__ xw, const float* __restrict__ dinv,
                            const float* __restrict__ b2, const float* __restrict__ xc1,
                            const int* __restrict__ idx, float* __restrict__ out, int N) {
    int t = blockIdx.x * blockDim.x + threadIdx.x;
    if (t >= N * 25) return;
    int n = t / 25, jq = t % 25;
    float dn = dinv[n];
    float4 acc = {0.f, 0.f, 0.f, 0.f};
    int e1 = rs[n + 1];
    for (int e = rs[n]; e < e1; ++e) {
        int s = esrc[e];
        float ds = dinv[s];
        float4 xs = ((const float4*)xw)[s * 25 + jq];
        acc.x = fmaf(xs.x, ds, acc.x);
        acc.y = fmaf(xs.y, ds, acc.y);
        acc.z = fmaf(xs.z, ds, acc.z);
        acc.w = fmaf(xs.w, ds, acc.w);
    }
    float4 xs = ((const float4*)xw)[t];
    float4 bq = ((const float4*)b2)[jq];
    float dn2 = dn * dn;
    float4 v;
    v.x = fmaxf(fmaf(acc.x, dn, fmaf(xs.x, dn2, bq.x)), 0.f);
    v.y = fmaxf(fmaf(acc.y, dn, fmaf(xs.y, dn2, bq.y)), 0.f);
    v.z = fmaxf(fmaf(acc.z, dn, fmaf(xs.z, dn2, bq.z)), 0.f);
    v.w = fmaxf(fmaf(acc.w, dn, fmaf(xs.w, dn2, bq.w)), 0.f);
    float4 rv = ((const float4*)xc1)[(long)idx[n] * 25 + jq];
    ((float4*)out)[n * 50 + jq] = v;
    ((float4*)out)[n * 50 + 25 + jq] = rv;
}

// ---------------------------------------------------------------------------
extern "C" void kernel_launch(void* const* d_in, const int* in_sizes, int n_in,
                              void* d_out, int out_size, void* d_ws, size_t ws_size,
                              hipStream_t stream) {
    const int*   feat    = (const int*)d_in[0];
    const int*   edges   = (const int*)d_in[1];
    const int*   indices = (const int*)d_in[2];
    const float* h0      = (const float*)d_in[3];
    const float* emb     = (const float*)d_in[4];
    const float* W_ih    = (const float*)d_in[5];
    const float* W_hh    = (const float*)d_in[6];
    const float* b_ih    = (const float*)d_in[7];
    const float* b_hh    = (const float*)d_in[8];
    const float* W1      = (const float*)d_in[9];
    const float* b1      = (const float*)d_in[10];
    const float* W2      = (const float*)d_in[11];
    const float* b2      = (const float*)d_in[12];
    float* out = (float*)d_out;

    const int N = in_sizes[2];
    const int E = in_sizes[1] / 2;
    const int V = in_sizes[4] / D_IN;
    const int* src = edges;
    const int* dst = edges + E;

    float* ws   = (float*)d_ws;
    float* hbuf = ws;                         // N*100
    float* Wemb = hbuf + (long)N * H;         // V*300 (reused as xw after GRU)
    float* xw   = Wemb;                       // reuse: N*100
    float* xc1  = Wemb + (long)V * 300;       // N*100
    float* xbig = xc1 + (long)N * 100;        // N*200 (unused; kept for layout)
    float* dinv = xbig + (long)N * 200;       // N
    short* Bhi  = (short*)(dinv + N);         // 43008 bf16 (GRU W_hh)
    short* Blo  = Bhi + 43008;                // 43008
    short* PihH = Blo + 43008;                // 38912 (W_ih: CT=19, KS=4)
    short* PihL = PihH + 38912;               // 38912
    short* P1H  = PihL + 38912;               // 14336 (W1: CT=7, KS=4)
    short* P1L  = P1H + 14336;                // 14336
    short* P2H  = P1L + 14336;                // 25088 (W2: CT=7, KS=7)
    short* P2L  = P2H + 25088;                // 25088
    int*   degi = (int*)(P2L + 25088);        // N
    int*   rs   = degi + N;                   // N+1
    int*   cursor = rs + N + 1;               // N
    int*   esrc = cursor + N;                 // E
    int*   bsum = esrc + E;                   // ceil(N/256) partials
    (void)ws_size; (void)n_in; (void)out_size;

    const int B = 256;
    const int Gs = (N + 255) / 256;

    hipMemsetAsync(degi, 0, (size_t)N * sizeof(int), stream);
    k_deg<<<(E + B - 1) / B, B, 0, stream>>>(dst, degi, E);
    k_scan_bsum<<<Gs, 256, 0, stream>>>(degi, bsum, N);
    k_scan_part<<<1, 1024, 0, stream>>>(bsum, Gs);
    k_scan_emit<<<Gs, 256, 0, stream>>>(degi, bsum, rs, cursor, dinv, N, E);
    k_scatter<<<(E + B - 1) / B, B, 0, stream>>>(src, dst, cursor, esrc, E);

    k_packall<<<(121344 + B - 1) / B, B, 0, stream>>>(W_hh, W_ih, W1, W2,
                                                      Bhi, Blo, PihH, PihL,
                                                      P1H, P1L, P2H, P2L);

    // Wemb = emb @ W_ih^T + b_ih, interleaved [v][jc][g]
    k_gemm<4><<<(V + 63) / 64, 448, 0, stream>>>(emb, 100, V, PihH, PihL, b_ih,
                                                 Wemb, 300, 300, 19, 1);

    k_gru_mfma<<<(N + 47) / 48, 448, 0, stream>>>(feat, h0, Wemb, Bhi, Blo, b_hh, hbuf, N);

    {
        // xw = hbuf @ W1
        k_gemm<4><<<(N + 63) / 64, 448, 0, stream>>>(hbuf, 100, N, P1H, P1L, nullptr,
                                                     xw, 100, 100, 7, 0);
        int nquads = N * 25;
        k_conv1_fin<<<(nquads + B - 1) / B, B, 0, stream>>>(rs, esrc, xw, dinv, b1, xc1, N);
        // xw = relu([xc1, hn[idx]]) @ W2  (concat staged in-kernel)
        k_gemm_cat<<<(N + 63) / 64, 448, 0, stream>>>(xc1, hbuf, indices, N,
                                                      P2H, P2L, xw, 7);
        k_conv2_fin<<<(nquads + B - 1) / B, B, 0, stream>>>(rs, esrc, xw, dinv, b2, xc1,
                                                            indices, out, N);
    }
}